// Round 2
// baseline (4397.269 us; speedup 1.0000x reference)
//
#include <hip/hip_runtime.h>

#define N_NODES 50000
#define N_EDGES 1600000
#define F_IN    32
#define HID     64
#define F_OUT   128

// ---------------------------------------------------------------------------
// Kernel 1: fused per-edge MLP (concat(x_j, pos_j - pos_i) -> Lin+ReLU x2)
//           + segment-max via atomicMax on float bit pattern (values >= 0).
// Edge-per-lane: each thread computes the full 35->64->64 MLP for one edge.
// h1 round-trips through LDS ([k][tid] layout, 2-way bank alias = free) so
// both layers keep their 64 accumulators in registers with static indexing.
// Aggregation target: first 64 floats of each 128-float output row (in-place
// in d_out, so no workspace-size assumption).
// ---------------------------------------------------------------------------
template <int T>
__global__ __launch_bounds__(T) void edge_mlp_kernel(
    const float* __restrict__ x,
    const float* __restrict__ pos,
    const int* __restrict__ ei,         // [2, N_EDGES] as int32: src row, dst row
    const float* __restrict__ W1, const float* __restrict__ b1,
    const float* __restrict__ W2, const float* __restrict__ b2,
    unsigned int* __restrict__ aggbits) // d_out as uint bits, [N_NODES, F_OUT], zeroed
{
    __shared__ float h1s[HID * T];      // T=128 -> 32 KiB

    const int t = threadIdx.x;
    const long long gid = (long long)blockIdx.x * T + t;
    const long long total = (long long)N_EDGES + N_NODES;
    const bool active = gid < total;

    int s = 0, d = 0;
    if (active) {
        if (gid < N_EDGES) {
            s = ei[gid];
            d = ei[N_EDGES + gid];
        } else {
            s = d = (int)(gid - N_EDGES);   // self loop
        }
    }

    // ---- layer 1: acc[k] = b1[k] + sum_c msg[c] * W1[c][k] ----
    float acc[HID];
    #pragma unroll
    for (int k = 0; k < HID; ++k) acc[k] = b1[k];

    const float4* xs4 = (const float4*)(x + (long long)s * F_IN);
    #pragma unroll 1
    for (int cc = 0; cc < F_IN / 4; ++cc) {
        const float4 m4 = xs4[cc];
        const float mv[4] = {m4.x, m4.y, m4.z, m4.w};
        #pragma unroll
        for (int q = 0; q < 4; ++q) {
            const float m = mv[q];
            const float* w = W1 + (cc * 4 + q) * HID;   // wave-uniform -> s_load
            #pragma unroll
            for (int k = 0; k < HID; ++k) acc[k] = fmaf(m, w[k], acc[k]);
        }
    }
    // pos part (features 32..34): pos_j - pos_i
    {
        float pd[3];
        #pragma unroll
        for (int a = 0; a < 3; ++a)
            pd[a] = pos[(long long)s * 3 + a] - pos[(long long)d * 3 + a];
        #pragma unroll
        for (int a = 0; a < 3; ++a) {
            const float m = pd[a];
            const float* w = W1 + (F_IN + a) * HID;
            #pragma unroll
            for (int k = 0; k < HID; ++k) acc[k] = fmaf(m, w[k], acc[k]);
        }
    }

    // ---- relu -> LDS (each thread uses only its own column; no barrier) ----
    #pragma unroll
    for (int k = 0; k < HID; ++k) h1s[k * T + t] = fmaxf(acc[k], 0.0f);

    // ---- layer 2: acc[k] = b2[k] + sum_j h1[j] * W2[j][k] ----
    #pragma unroll
    for (int k = 0; k < HID; ++k) acc[k] = b2[k];

    #pragma unroll 2
    for (int j = 0; j < HID; ++j) {
        const float m = h1s[j * T + t];
        const float* w = W2 + j * HID;
        #pragma unroll
        for (int k = 0; k < HID; ++k) acc[k] = fmaf(m, w[k], acc[k]);
    }

    // ---- relu + segment-max scatter into out-row's first 64 floats ----
    if (active) {
        unsigned int* ap = aggbits + (long long)d * F_OUT;
        #pragma unroll
        for (int k = 0; k < HID; ++k) {
            const float h = fmaxf(acc[k], 0.0f);
            atomicMax(ap + k, __float_as_uint(h));   // h >= 0: uint order == float order
        }
    }
}

// ---------------------------------------------------------------------------
// Kernel 2: out[n][o] = bg[o] + sum_j agg[n][j] * Wg[j][o], in place.
// One wave per node (grid-stride). Lane holds Wg[:, lane] and Wg[:, lane+64]
// in registers (loaded once); agg row read coalesced (1 float/lane) and
// broadcast via __shfl. Read->write hazard is wave-internal registers: safe.
// ---------------------------------------------------------------------------
__global__ __launch_bounds__(256) void out_gemm_kernel(
    float* __restrict__ out,            // [N_NODES, F_OUT]; first 64/row = agg
    const float* __restrict__ Wg,       // [HID, F_OUT]
    const float* __restrict__ bg)       // [F_OUT]
{
    const int lane  = threadIdx.x & 63;
    const int wave  = blockIdx.x * (blockDim.x >> 6) + (threadIdx.x >> 6);
    const int nwav  = gridDim.x * (blockDim.x >> 6);

    // Wg columns `lane` and `lane+64` in registers (coalesced: 256B/inst)
    float w1r[HID], w2r[HID];
    #pragma unroll
    for (int j = 0; j < HID; ++j) {
        w1r[j] = Wg[j * F_OUT + lane];
        w2r[j] = Wg[j * F_OUT + 64 + lane];
    }
    const float bga = bg[lane];
    const float bgb = bg[64 + lane];

    for (int n = wave; n < N_NODES; n += nwav) {
        float* row = out + (long long)n * F_OUT;
        const float a = row[lane];          // agg[n][lane]
        float y1 = bga, y2 = bgb;
        #pragma unroll
        for (int j = 0; j < HID; ++j) {
            const float aj = __shfl(a, j, 64);
            y1 = fmaf(aj, w1r[j], y1);
            y2 = fmaf(aj, w2r[j], y2);
        }
        row[lane]      = y1;
        row[64 + lane] = y2;
    }
}

extern "C" void kernel_launch(void* const* d_in, const int* in_sizes, int n_in,
                              void* d_out, int out_size, void* d_ws, size_t ws_size,
                              hipStream_t stream) {
    const float* x   = (const float*)d_in[0];
    const float* pos = (const float*)d_in[1];
    const int*   ei  = (const int*)d_in[2];    // harness delivers integers as int32
    const float* W1  = (const float*)d_in[3];
    const float* b1  = (const float*)d_in[4];
    const float* W2  = (const float*)d_in[5];
    const float* b2  = (const float*)d_in[6];
    const float* Wg  = (const float*)d_in[7];
    const float* bg  = (const float*)d_in[8];
    float* out = (float*)d_out;

    // zero d_out: agg identity (relu outputs >= 0, so 0.0f bits = 0x0 works)
    hipMemsetAsync(out, 0, (size_t)out_size * sizeof(float), stream);

    constexpr int T = 128;
    const long long total = (long long)N_EDGES + N_NODES;
    const int blocks1 = (int)((total + T - 1) / T);
    edge_mlp_kernel<T><<<blocks1, T, 0, stream>>>(
        x, pos, ei, W1, b1, W2, b2, (unsigned int*)out);

    out_gemm_kernel<<<512, 256, 0, stream>>>(out, Wg, bg);
}

// Round 3
// 617.716 us; speedup vs baseline: 7.1186x; 7.1186x over previous
//
#include <hip/hip_runtime.h>

#define N_NODES 50000
#define N_EDGES 1600000
#define F_IN    32
#define HID     64
#define F_OUT   128

// ---------------------------------------------------------------------------
// Kernel A: per-node precompute Q[n] = b1 + x_n @ W1[0:32,:]  (the x-part of
// layer 1, which depends only on the source node), stored in d_out cols 0-63.
// Cols 64-127 zeroed = atomicMax identity (relu outputs >= 0).
// ---------------------------------------------------------------------------
__global__ __launch_bounds__(256) void node_pre_kernel(
    const float* __restrict__ x,
    const float* __restrict__ W1, const float* __restrict__ b1,
    float* __restrict__ out)            // [N_NODES, 128]
{
    const int n = blockIdx.x * 256 + threadIdx.x;
    if (n >= N_NODES) return;

    float acc[HID];
    #pragma unroll
    for (int k = 0; k < HID; ++k) acc[k] = b1[k];

    const float4* x4 = (const float4*)(x + (long long)n * F_IN);
    #pragma unroll 1
    for (int c4 = 0; c4 < F_IN / 4; ++c4) {
        const float4 v = x4[c4];
        const float mv[4] = {v.x, v.y, v.z, v.w};
        #pragma unroll
        for (int q = 0; q < 4; ++q) {
            const float* w = W1 + (c4 * 4 + q) * HID;   // wave-uniform
            #pragma unroll
            for (int k = 0; k < HID; ++k) acc[k] = fmaf(mv[q], w[k], acc[k]);
        }
    }

    float4* o4 = (float4*)(out + (long long)n * F_OUT);
    #pragma unroll
    for (int k4 = 0; k4 < HID / 4; ++k4)
        o4[k4] = make_float4(acc[4*k4], acc[4*k4+1], acc[4*k4+2], acc[4*k4+3]);
    const float4 z = make_float4(0.f, 0.f, 0.f, 0.f);
    #pragma unroll
    for (int k4 = 0; k4 < HID / 4; ++k4) o4[HID/4 + k4] = z;
}

// ---------------------------------------------------------------------------
// Kernel B: per-edge layer1 (Q[s] + (pos_s-pos_d)@W1p) -> relu -> layer2 ->
// relu -> segment-max. One wave per block (T=64), edge-per-lane for the MLP,
// then transpose h2 through LDS so the atomicMax phase is one COALESCED
// 256B-row atomic per edge (8 sectors) instead of 64 scattered sectors.
// Load-test-skip: only lanes whose candidate beats the current agg issue the
// atomic (agg is monotone non-decreasing, so a stale read only causes an
// extra atomic, never a missed update).
// ---------------------------------------------------------------------------
__global__ __launch_bounds__(64) void edge_kernel(
    const float* __restrict__ qagg,     // d_out: [N,128] cols 0-63 = Q
    const float* __restrict__ pos,
    const int* __restrict__ ei,         // [2, N_EDGES] int32: src row, dst row
    const float* __restrict__ W1p,      // W1 rows 32..34, [3, 64]
    const float* __restrict__ W2, const float* __restrict__ b2,
    unsigned int* __restrict__ aggbits) // d_out bits; agg at cols 64-127
{
    __shared__ float lds[HID * 65];     // h1 phase uses [k*64+t]; h2 [t*65+k]

    const int t = threadIdx.x;
    const long long gid = (long long)blockIdx.x * 64 + t;
    const bool is_edge = gid < N_EDGES;
    const bool active  = gid < (long long)N_EDGES + N_NODES;

    int s = 0, d = 0;
    if (is_edge) {
        s = ei[gid];
        d = ei[N_EDGES + gid];
    } else if (active) {
        s = d = (int)(gid - N_EDGES);   // self loop: pos diff = 0
    }

    // ---- layer 1: acc = Q[s] + (pos_s - pos_d) @ W1p ----
    float acc[HID];
    const float4* q4 = (const float4*)(qagg + (long long)s * F_OUT);
    #pragma unroll
    for (int c = 0; c < HID / 4; ++c) {
        const float4 v = q4[c];
        acc[4*c] = v.x; acc[4*c+1] = v.y; acc[4*c+2] = v.z; acc[4*c+3] = v.w;
    }
    {
        float pd[3];
        #pragma unroll
        for (int a = 0; a < 3; ++a)
            pd[a] = pos[(long long)s * 3 + a] - pos[(long long)d * 3 + a];
        #pragma unroll
        for (int a = 0; a < 3; ++a) {
            const float* w = W1p + a * HID;     // wave-uniform
            #pragma unroll
            for (int k = 0; k < HID; ++k) acc[k] = fmaf(pd[a], w[k], acc[k]);
        }
    }

    // ---- relu -> LDS, layout [k][t] (2-way bank alias = free) ----
    #pragma unroll
    for (int k = 0; k < HID; ++k) lds[k * 64 + t] = fmaxf(acc[k], 0.0f);
    __syncthreads();

    // ---- layer 2 ----
    #pragma unroll
    for (int k = 0; k < HID; ++k) acc[k] = b2[k];
    #pragma unroll 2
    for (int j = 0; j < HID; ++j) {
        const float m = lds[j * 64 + t];
        const float* w = W2 + j * HID;          // wave-uniform
        #pragma unroll
        for (int k = 0; k < HID; ++k) acc[k] = fmaf(m, w[k], acc[k]);
    }
    __syncthreads();                            // all h1 reads done

    // ---- relu + transpose: h2 -> LDS [t][k] with pad 65 (conflict-free) ----
    #pragma unroll
    for (int k = 0; k < HID; ++k) lds[t * 65 + k] = fmaxf(acc[k], 0.0f);
    __syncthreads();

    // ---- coalesced segment-max: one row-atomic per edge ----
    const int dv = active ? d : -1;
    #pragma unroll 1
    for (int e = 0; e < 64; ++e) {
        const int de = __shfl(dv, e, 64);
        if (de < 0) continue;                   // wave-uniform
        const float h = lds[e * 65 + t];        // channel t of edge e
        unsigned int* ap = aggbits + (long long)de * F_OUT + HID;
        const float cur = __uint_as_float(ap[t]);   // fast-path load
        if (h > cur)
            atomicMax(ap + t, __float_as_uint(h));  // h>=0: uint order==float
    }
}

// ---------------------------------------------------------------------------
// Kernel C: out[n] = agg[n] @ Wg + bg, in place (reads cols 64-127, writes
// all 128). One wave per node; Wg columns in registers; agg broadcast via
// shfl. Read-before-write is wave-internal registers: race-free.
// ---------------------------------------------------------------------------
__global__ __launch_bounds__(256) void out_gemm_kernel(
    float* __restrict__ out,            // [N_NODES, 128]
    const float* __restrict__ Wg,       // [HID, F_OUT]
    const float* __restrict__ bg)       // [F_OUT]
{
    const int lane = threadIdx.x & 63;
    const int wave = blockIdx.x * (blockDim.x >> 6) + (threadIdx.x >> 6);
    const int nwav = gridDim.x * (blockDim.x >> 6);

    float w1r[HID], w2r[HID];
    #pragma unroll
    for (int j = 0; j < HID; ++j) {
        w1r[j] = Wg[j * F_OUT + lane];
        w2r[j] = Wg[j * F_OUT + 64 + lane];
    }
    const float bga = bg[lane];
    const float bgb = bg[64 + lane];

    for (int n = wave; n < N_NODES; n += nwav) {
        float* row = out + (long long)n * F_OUT;
        const float a = row[64 + lane];     // agg[n][lane]
        float y1 = bga, y2 = bgb;
        #pragma unroll
        for (int j = 0; j < HID; ++j) {
            const float aj = __shfl(a, j, 64);
            y1 = fmaf(aj, w1r[j], y1);
            y2 = fmaf(aj, w2r[j], y2);
        }
        row[lane]      = y1;
        row[64 + lane] = y2;
    }
}

extern "C" void kernel_launch(void* const* d_in, const int* in_sizes, int n_in,
                              void* d_out, int out_size, void* d_ws, size_t ws_size,
                              hipStream_t stream) {
    const float* x   = (const float*)d_in[0];
    const float* pos = (const float*)d_in[1];
    const int*   ei  = (const int*)d_in[2];    // harness delivers integers as int32
    const float* W1  = (const float*)d_in[3];
    const float* b1  = (const float*)d_in[4];
    const float* W2  = (const float*)d_in[5];
    const float* b2  = (const float*)d_in[6];
    const float* Wg  = (const float*)d_in[7];
    const float* bg  = (const float*)d_in[8];
    float* out = (float*)d_out;

    // A: Q into cols 0-63, zero cols 64-127 (covers the whole poisoned d_out)
    node_pre_kernel<<<(N_NODES + 255) / 256, 256, 0, stream>>>(x, W1, b1, out);

    // B: fused edge MLP + coalesced skip-tested atomic segment-max
    const long long total = (long long)N_EDGES + N_NODES;
    const int blocksB = (int)((total + 63) / 64);
    edge_kernel<<<blocksB, 64, 0, stream>>>(
        out, pos, ei, W1 + F_IN * HID, W2, b2, (unsigned int*)out);

    // C: out = agg @ Wg + bg, in place
    out_gemm_kernel<<<512, 256, 0, stream>>>(out, Wg, bg);
}

// Round 4
// 616.461 us; speedup vs baseline: 7.1331x; 1.0020x over previous
//
#include <hip/hip_runtime.h>

#define N_NODES 50000
#define N_EDGES 1600000
#define N_TOTAL (N_EDGES + N_NODES)   // edges + self loops
#define F_IN    32
#define HID     64
#define F_OUT   128

// ---------------------------------------------------------------------------
// Kernel A: Q[n] = b1 + x_n @ W1[0:32,:] into d_out cols 0-63; zero cols
// 64-127 (atomicMax identity, relu >= 0). Also init cnt[n] = 1 (self-loop
// slot for the counting sort).
// ---------------------------------------------------------------------------
__global__ __launch_bounds__(256) void node_pre_kernel(
    const float* __restrict__ x,
    const float* __restrict__ W1, const float* __restrict__ b1,
    float* __restrict__ out, int* __restrict__ cnt)
{
    const int n = blockIdx.x * 256 + threadIdx.x;
    if (n >= N_NODES) return;
    cnt[n] = 1;                          // self-loop reserved slot

    float acc[HID];
    #pragma unroll
    for (int k = 0; k < HID; ++k) acc[k] = b1[k];

    const float4* x4 = (const float4*)(x + (long long)n * F_IN);
    #pragma unroll 1
    for (int c4 = 0; c4 < F_IN / 4; ++c4) {
        const float4 v = x4[c4];
        const float mv[4] = {v.x, v.y, v.z, v.w};
        #pragma unroll
        for (int q = 0; q < 4; ++q) {
            const float* w = W1 + (c4 * 4 + q) * HID;   // wave-uniform
            #pragma unroll
            for (int k = 0; k < HID; ++k) acc[k] = fmaf(mv[q], w[k], acc[k]);
        }
    }

    float4* o4 = (float4*)(out + (long long)n * F_OUT);
    #pragma unroll
    for (int k4 = 0; k4 < HID / 4; ++k4)
        o4[k4] = make_float4(acc[4*k4], acc[4*k4+1], acc[4*k4+2], acc[4*k4+3]);
    const float4 z = make_float4(0.f, 0.f, 0.f, 0.f);
    #pragma unroll
    for (int k4 = 0; k4 < HID / 4; ++k4) o4[HID/4 + k4] = z;
}

// ---------------------------------------------------------------------------
// Kernel B1: histogram of real-edge destinations (cnt starts at 1 per node).
// ---------------------------------------------------------------------------
__global__ __launch_bounds__(256) void hist_kernel(
    const int* __restrict__ ei, int* __restrict__ cnt)
{
    const int gid = blockIdx.x * 256 + threadIdx.x;
    if (gid >= N_EDGES) return;
    atomicAdd(&cnt[ei[N_EDGES + gid]], 1);
}

// ---------------------------------------------------------------------------
// Kernel B2: exclusive scan of cnt[0..N-1] -> ptrA[0..N] and cursor copy.
// Single 1024-thread block; shfl-based wave scans, 4 barriers per chunk.
// ---------------------------------------------------------------------------
__global__ __launch_bounds__(1024) void scan_kernel(
    const int* __restrict__ cnt, int* __restrict__ ptrA, int* __restrict__ cursor)
{
    __shared__ int wsum[16];
    __shared__ int carry_s;
    const int t = threadIdx.x, lane = t & 63, w = t >> 6;
    if (t == 0) carry_s = 0;
    __syncthreads();

    for (int base = 0; base < N_NODES; base += 1024) {
        const int i = base + t;
        const int v = (i < N_NODES) ? cnt[i] : 0;
        int x = v;                                   // wave inclusive scan
        #pragma unroll
        for (int dd = 1; dd < 64; dd <<= 1) {
            const int y = __shfl_up(x, dd, 64);
            if (lane >= dd) x += y;
        }
        if (lane == 63) wsum[w] = x;
        __syncthreads();
        if (w == 0 && lane < 16) {                   // scan the 16 wave sums
            int y = wsum[lane];
            #pragma unroll
            for (int dd = 1; dd < 16; dd <<= 1) {
                const int z = __shfl_up(y, dd, 64);
                if (lane >= dd) y += z;
            }
            wsum[lane] = y;
        }
        __syncthreads();
        const int carry = carry_s;
        const int excl = carry + (w ? wsum[w - 1] : 0) + x - v;
        if (i < N_NODES) { ptrA[i] = excl; cursor[i] = excl; }
        __syncthreads();
        if (t == 1023) carry_s = carry + wsum[15];
        __syncthreads();
    }
    if (threadIdx.x == 0) ptrA[N_NODES] = carry_s;   // == N_TOTAL
}

// ---------------------------------------------------------------------------
// Kernel B3: scatter edges (+self loops) into dst-sorted order.
// ---------------------------------------------------------------------------
__global__ __launch_bounds__(256) void scatter_kernel(
    const int* __restrict__ ei, int* __restrict__ cursor,
    int* __restrict__ s_src, int* __restrict__ s_dst)
{
    const int gid = blockIdx.x * 256 + threadIdx.x;
    if (gid >= N_TOTAL) return;
    int s, d;
    if (gid < N_EDGES) { s = ei[gid]; d = ei[N_EDGES + gid]; }
    else               { s = d = gid - N_EDGES; }
    const int p = atomicAdd(&cursor[d], 1);
    s_src[p] = s; s_dst[p] = d;
}

// ---------------------------------------------------------------------------
// Kernel C: fused edge MLP over dst-sorted edges + run-combined segment-max.
// One wave per block, edge-per-lane MLP (as round 3), transpose via LDS, then
// a single pass over the 64 edges combining equal-dst runs in registers and
// issuing ONE load-tested coalesced row-atomicMax per run (~2-3 per wave).
// ---------------------------------------------------------------------------
__global__ __launch_bounds__(64) void gather_kernel(
    const float* __restrict__ qagg,     // d_out: [N,128] cols 0-63 = Q
    const float* __restrict__ pos,
    const int* __restrict__ s_src, const int* __restrict__ s_dst,
    const float* __restrict__ W1p,      // W1 rows 32..34, [3, 64]
    const float* __restrict__ W2, const float* __restrict__ b2,
    unsigned int* __restrict__ aggbits) // d_out bits; agg at cols 64-127
{
    __shared__ float lds[HID * 65];     // h1 phase [k*64+t]; h2 phase [t*65+k]

    const int t = threadIdx.x;
    const long long gid = (long long)blockIdx.x * 64 + t;
    const bool active = gid < N_TOTAL;

    int s = 0, di = 0, dv = -1;
    if (active) { s = s_src[gid]; di = s_dst[gid]; dv = di; }

    // ---- layer 1: acc = Q[s] + (pos_s - pos_d) @ W1p ----
    float acc[HID];
    const float4* q4 = (const float4*)(qagg + (long long)s * F_OUT);
    #pragma unroll
    for (int c = 0; c < HID / 4; ++c) {
        const float4 v = q4[c];
        acc[4*c] = v.x; acc[4*c+1] = v.y; acc[4*c+2] = v.z; acc[4*c+3] = v.w;
    }
    {
        float pd[3];
        #pragma unroll
        for (int a = 0; a < 3; ++a)
            pd[a] = pos[(long long)s * 3 + a] - pos[(long long)di * 3 + a];
        #pragma unroll
        for (int a = 0; a < 3; ++a) {
            const float* w = W1p + a * HID;     // wave-uniform
            #pragma unroll
            for (int k = 0; k < HID; ++k) acc[k] = fmaf(pd[a], w[k], acc[k]);
        }
    }

    // ---- relu -> LDS [k][t] (2-way bank alias = free) ----
    #pragma unroll
    for (int k = 0; k < HID; ++k) lds[k * 64 + t] = fmaxf(acc[k], 0.0f);
    __syncthreads();

    // ---- layer 2 ----
    #pragma unroll
    for (int k = 0; k < HID; ++k) acc[k] = b2[k];
    #pragma unroll 2
    for (int j = 0; j < HID; ++j) {
        const float m = lds[j * 64 + t];
        const float* w = W2 + j * HID;          // wave-uniform
        #pragma unroll
        for (int k = 0; k < HID; ++k) acc[k] = fmaf(m, w[k], acc[k]);
    }
    __syncthreads();

    // ---- relu + transpose: h2 -> LDS [t][k], pad 65 (conflict-free) ----
    #pragma unroll
    for (int k = 0; k < HID; ++k) lds[t * 65 + k] = fmaxf(acc[k], 0.0f);
    __syncthreads();

    // ---- run-combined segment-max (dst-sorted => equal dst contiguous) ----
    int   cur = __shfl(dv, 0, 64);
    float m   = lds[0 * 65 + t];
    #pragma unroll 1
    for (int e = 1; e < 64; ++e) {
        const int   de = __shfl(dv, e, 64);
        const float he = lds[e * 65 + t];
        if (de == cur) {
            m = fmaxf(m, he);
        } else {
            if (cur >= 0) {                     // flush run (wave-uniform)
                unsigned int* ap = aggbits + (long long)cur * F_OUT + HID;
                if (m > __uint_as_float(ap[t]))
                    atomicMax(ap + t, __float_as_uint(m));
            }
            cur = de; m = he;
        }
    }
    if (cur >= 0) {
        unsigned int* ap = aggbits + (long long)cur * F_OUT + HID;
        if (m > __uint_as_float(ap[t]))
            atomicMax(ap + t, __float_as_uint(m));
    }
}

// ---------------------------------------------------------------------------
// Kernel D: out[n] = agg[n] @ Wg + bg, in place (wave per node, Wg columns in
// registers, agg broadcast via shfl; wave-internal read->write is race-free).
// ---------------------------------------------------------------------------
__global__ __launch_bounds__(256) void out_gemm_kernel(
    float* __restrict__ out,            // [N_NODES, 128]
    const float* __restrict__ Wg,       // [HID, F_OUT]
    const float* __restrict__ bg)       // [F_OUT]
{
    const int lane = threadIdx.x & 63;
    const int wave = blockIdx.x * (blockDim.x >> 6) + (threadIdx.x >> 6);
    const int nwav = gridDim.x * (blockDim.x >> 6);

    float w1r[HID], w2r[HID];
    #pragma unroll
    for (int j = 0; j < HID; ++j) {
        w1r[j] = Wg[j * F_OUT + lane];
        w2r[j] = Wg[j * F_OUT + 64 + lane];
    }
    const float bga = bg[lane];
    const float bgb = bg[64 + lane];

    for (int n = wave; n < N_NODES; n += nwav) {
        float* row = out + (long long)n * F_OUT;
        const float a = row[64 + lane];
        float y1 = bga, y2 = bgb;
        #pragma unroll
        for (int j = 0; j < HID; ++j) {
            const float aj = __shfl(a, j, 64);
            y1 = fmaf(aj, w1r[j], y1);
            y2 = fmaf(aj, w2r[j], y2);
        }
        row[lane]      = y1;
        row[64 + lane] = y2;
    }
}

extern "C" void kernel_launch(void* const* d_in, const int* in_sizes, int n_in,
                              void* d_out, int out_size, void* d_ws, size_t ws_size,
                              hipStream_t stream) {
    const float* x   = (const float*)d_in[0];
    const float* pos = (const float*)d_in[1];
    const int*   ei  = (const int*)d_in[2];    // harness delivers integers as int32
    const float* W1  = (const float*)d_in[3];
    const float* b1  = (const float*)d_in[4];
    const float* W2  = (const float*)d_in[5];
    const float* b2  = (const float*)d_in[6];
    const float* Wg  = (const float*)d_in[7];
    const float* bg  = (const float*)d_in[8];
    float* out = (float*)d_out;

    // workspace layout (ints): needs ~13.8 MB of d_ws
    int* ws     = (int*)d_ws;
    int* cnt    = ws;                       // [50000]
    int* ptrA   = ws + 50048;               // [50001]
    int* cursor = ws + 100096;              // [50000]
    int* s_src  = ws + 150144;              // [N_TOTAL]
    int* s_dst  = ws + 150144 + 1650048;    // [N_TOTAL]

    // A: Q + zero agg + cnt=1
    node_pre_kernel<<<(N_NODES + 255) / 256, 256, 0, stream>>>(x, W1, b1, out, cnt);
    // B: counting sort by dst
    hist_kernel<<<(N_EDGES + 255) / 256, 256, 0, stream>>>(ei, cnt);
    scan_kernel<<<1, 1024, 0, stream>>>(cnt, ptrA, cursor);
    scatter_kernel<<<(N_TOTAL + 255) / 256, 256, 0, stream>>>(ei, cursor, s_src, s_dst);
    // C: fused MLP + run-combined segment-max over sorted edges
    gather_kernel<<<(N_TOTAL + 63) / 64, 64, 0, stream>>>(
        out, pos, s_src, s_dst, W1 + F_IN * HID, W2, b2, (unsigned int*)out);
    // D: out = agg @ Wg + bg, in place
    out_gemm_kernel<<<512, 256, 0, stream>>>(out, Wg, bg);
}